// Round 10
// baseline (189.494 us; speedup 1.0000x reference)
//
#include <hip/hip_runtime.h>
#include <hip/hip_bf16.h>

#define B_ 2
#define SQ_ 2048
#define SKV_ 2048
#define D_ 1024
#define H_ 16
#define HD_ 64

typedef unsigned short u16;
typedef float f32x4 __attribute__((ext_vector_type(4)));
typedef float f32x16 __attribute__((ext_vector_type(16)));
typedef short s16x8 __attribute__((ext_vector_type(8)));

__device__ __forceinline__ u16 f2bf(float f) {
  union { float f; unsigned u; } v; v.f = f;
  return (u16)((v.u + 0x7FFFu + ((v.u >> 16) & 1u)) >> 16);
}
__device__ __forceinline__ float bf2f(u16 h) {
  union { unsigned u; float f; } v; v.u = ((unsigned)h) << 16;
  return v.f;
}
// pack bf16(s1)<<16 | bf16(s0), round-half-up: 2 adds + 1 v_perm
__device__ __forceinline__ unsigned pack2bf(float s0, float s1) {
  union { float f; unsigned u; } a, b; a.f = s0; b.f = s1;
  return __builtin_amdgcn_perm(b.u + 0x8000u, a.u + 0x8000u, 0x07060302u);
}
__device__ __forceinline__ f32x4 mfma16(s16x8 a, s16x8 b, f32x4 c) {
  return __builtin_amdgcn_mfma_f32_16x16x32_bf16(a, b, c, 0, 0, 0);
}
__device__ __forceinline__ f32x16 mfma32(s16x8 a, s16x8 b, f32x16 c) {
  return __builtin_amdgcn_mfma_f32_32x32x16_bf16(a, b, c, 0, 0, 0);
}
// async 16B/lane global -> LDS (dest = wave-uniform base + lane*16)
__device__ __forceinline__ void async16(const u16* g, u16* l) {
  __builtin_amdgcn_global_load_lds(
      (const __attribute__((address_space(1))) unsigned int*)g,
      (__attribute__((address_space(3))) unsigned int*)l, 16, 0, 0);
}

// ---------------- fused prep: cast q, cast kv, transpose 3 weights ----------------
__device__ __forceinline__ void tr_tile(const float* __restrict__ in, u16* __restrict__ out,
                                        int R, int C, int cx, int ry, int t) {
  __shared__ u16 tile[32][33];
  int tx = t & 31, ty = t >> 5;
  int c0 = cx * 32, r0 = ry * 32;
#pragma unroll
  for (int i = 0; i < 4; i++)
    tile[ty + i * 8][tx] = f2bf(in[(size_t)(r0 + ty + i * 8) * C + c0 + tx]);
  __syncthreads();
#pragma unroll
  for (int i = 0; i < 4; i++)
    out[(size_t)(c0 + ty + i * 8) * R + r0 + tx] = tile[tx][ty + i * 8];
}

__device__ __forceinline__ void cast4(const float* __restrict__ in, u16* __restrict__ out,
                                      int i) {
  float4 f = *(const float4*)(in + i);
  ushort4 o;
  o.x = f2bf(f.x); o.y = f2bf(f.y); o.z = f2bf(f.z); o.w = f2bf(f.w);
  *(ushort4*)(out + i) = o;
}

__global__ __launch_bounds__(256) void prep_kernel(
    const float* __restrict__ q, u16* __restrict__ q_bf,
    const float* __restrict__ kv, u16* __restrict__ kv_bf,
    const float* __restrict__ Wq, u16* __restrict__ WqT,
    const float* __restrict__ Wkv, u16* __restrict__ WkvT,
    const float* __restrict__ Wproj, u16* __restrict__ WprT) {
  int bid = blockIdx.x, t = threadIdx.x;
  if (bid < 4096) {
    cast4(q, q_bf, bid * 1024 + t * 4);
  } else if (bid < 8192) {
    cast4(kv, kv_bf, (bid - 4096) * 1024 + t * 4);
  } else if (bid < 9216) {
    int b2 = bid - 8192;
    tr_tile(Wq, WqT, 1024, 1024, b2 & 31, b2 >> 5, t);
  } else if (bid < 11264) {
    int b2 = bid - 9216;
    tr_tile(Wkv, WkvT, 1024, 2048, b2 & 63, b2 >> 6, t);
  } else {
    int b2 = bid - 11264;
    tr_tile(Wproj, WprT, 1024, 1024, b2 & 31, b2 >> 5, t);
  }
}

// ------- m97-style GEMM body: C(BMxBN) = A(BM x K) * BT(BN x K)^T -------
// R10: T2 XOR-swizzle on the As/Bs 16B slots (rule #21 both-sides): async16's GLOBAL
// source col-quad is pre-swizzled (gcol = ((l&3)^((l>>2)&3))*8) and the fragment read
// uses rq = quad ^ (l16&3). Valid since mw/nw/i*16 are ==0 mod 4 -> row&3 == l16&3,
// so rq is a per-lane constant (zero per-iter cost). 8-way -> 4-way read conflicts.
// LNV=true (kv V-half): LayerNorm rows over the 64-wide head owned by each wave,
// transpose through a per-wave-private LDS tile, store to vt[b,h,d,s].
template <int BM, int BN, bool OUT_BF16, bool LNV>
__device__ __forceinline__ void gemm_body(const u16* __restrict__ A,
                                          const u16* __restrict__ BT,
                                          void* __restrict__ Cout,
                                          int m0, int n0, int N, int K,
                                          u16* __restrict__ smem,
                                          const float* __restrict__ gamma,
                                          const float* __restrict__ beta,
                                          u16* __restrict__ vt) {
  u16* As = smem;             // [BM][32]
  u16* Bs = smem + BM * 32;   // [BN][32]
  constexpr int AM = BM / 32, AN = BN / 32;
  int t = threadIdx.x, w = t >> 6, lane = t & 63;
  int l16 = lane & 15, quad = lane >> 4;
  int mw = (w >> 1) * (BM / 2), nw = (w & 1) * (BN / 2);
  int grow = w * 16 + (lane >> 2);
  int gcol = ((lane & 3) ^ ((lane >> 2) & 3)) * 8;  // pre-swizzled source quad
  int rq = quad ^ (l16 & 3);                        // swizzled read quad (per-lane const)

  f32x4 acc[AM][AN] = {};

  for (int kt = 0; kt < K; kt += 32) {
    __syncthreads();
#pragma unroll
    for (int j = 0; j < BM / 64; j++)
      async16(A + (size_t)(m0 + j * 64 + grow) * K + kt + gcol, &As[(j * 64 + w * 16) * 32]);
#pragma unroll
    for (int j = 0; j < BN / 64; j++)
      async16(BT + (size_t)(n0 + j * 64 + grow) * K + kt + gcol, &Bs[(j * 64 + w * 16) * 32]);
    __syncthreads();
    s16x8 af[AM], bf[AN];
#pragma unroll
    for (int i = 0; i < AM; i++) af[i] = *(const s16x8*)&As[(mw + i * 16 + l16) * 32 + rq * 8];
#pragma unroll
    for (int j = 0; j < AN; j++) bf[j] = *(const s16x8*)&Bs[(nw + j * 16 + l16) * 32 + rq * 8];
#pragma unroll
    for (int i = 0; i < AM; i++)
#pragma unroll
      for (int j = 0; j < AN; j++)
        acc[i][j] = mfma16(af[i], bf[j], acc[i][j]);
  }

  if constexpr (LNV) {
    // ---- fused LayerNorm over head dim + transpose to vt[b,h,d,s] ----
    __syncthreads();  // all waves done reading As/Bs; smem reusable as tiles
    u16* tile = smem + w * 4352;  // per-wave [64][68] u16 (8704 B), private
    int h = (n0 - 1024 + nw) >> 6;   // global head 0..15
    int b_ = m0 >> 11;
    int s0 = (m0 & 2047) + mw;
    float g4[4], be4[4];
#pragma unroll
    for (int j = 0; j < 4; j++) { g4[j] = gamma[j * 16 + l16]; be4[j] = beta[j * 16 + l16]; }
#pragma unroll
    for (int i = 0; i < 4; i++) {
      float mu[4], inv[4];
#pragma unroll
      for (int r = 0; r < 4; r++) {
        float x0 = acc[i][0][r], x1 = acc[i][1][r], x2 = acc[i][2][r], x3 = acc[i][3][r];
        float rs = x0 + x1 + x2 + x3;
        rs += __shfl_xor(rs, 1); rs += __shfl_xor(rs, 2);
        rs += __shfl_xor(rs, 4); rs += __shfl_xor(rs, 8);
        float m = rs * 0.015625f;
        float d0 = x0 - m, d1 = x1 - m, d2 = x2 - m, d3 = x3 - m;
        float vs = d0 * d0 + d1 * d1 + d2 * d2 + d3 * d3;
        vs += __shfl_xor(vs, 1); vs += __shfl_xor(vs, 2);
        vs += __shfl_xor(vs, 4); vs += __shfl_xor(vs, 8);
        mu[r] = m;
        inv[r] = rsqrtf(vs * 0.015625f + 1e-5f);
      }
#pragma unroll
      for (int j = 0; j < 4; j++) {
        ushort4 o;
        o.x = f2bf((acc[i][j][0] - mu[0]) * inv[0] * g4[j] + be4[j]);
        o.y = f2bf((acc[i][j][1] - mu[1]) * inv[1] * g4[j] + be4[j]);
        o.z = f2bf((acc[i][j][2] - mu[2]) * inv[2] * g4[j] + be4[j]);
        o.w = f2bf((acc[i][j][3] - mu[3]) * inv[3] * g4[j] + be4[j]);
        // tile[d = j*16+l16][s4 = i*16+quad*4]: 8B-aligned (stride 136 B)
        *(ushort4*)&tile[(size_t)(j * 16 + l16) * 68 + i * 16 + quad * 4] = o;
      }
    }
    // readout: lane-private region of this wave's tile (compiler orders via lgkmcnt)
    size_t vbase = ((size_t)((b_ * 16 + h) * 64)) * 2048 + s0;
#pragma unroll
    for (int p = 0; p < 4; p++) {
      int d = p * 16 + (lane >> 2);
      int sc = (lane & 3) * 16;
      uint2 a0 = *(uint2*)&tile[(size_t)d * 68 + sc];
      uint2 a1 = *(uint2*)&tile[(size_t)d * 68 + sc + 4];
      uint2 a2 = *(uint2*)&tile[(size_t)d * 68 + sc + 8];
      uint2 a3 = *(uint2*)&tile[(size_t)d * 68 + sc + 12];
      uint4 w0; w0.x = a0.x; w0.y = a0.y; w0.z = a1.x; w0.w = a1.y;
      uint4 w1; w1.x = a2.x; w1.y = a2.y; w1.z = a3.x; w1.w = a3.y;
      *(uint4*)(vt + vbase + (size_t)d * 2048 + sc) = w0;
      *(uint4*)(vt + vbase + (size_t)d * 2048 + sc + 8) = w1;
    }
    return;
  }

#pragma unroll
  for (int i = 0; i < AM; i++)
#pragma unroll
    for (int j = 0; j < AN; j++) {
      int col = n0 + nw + j * 16 + l16;
#pragma unroll
      for (int r = 0; r < 4; r++) {
        int row = m0 + mw + i * 16 + quad * 4 + r;
        float v = acc[i][j][r];
        if (OUT_BF16)
          ((u16*)Cout)[(size_t)row * N + col] = f2bf(v);
        else
          ((float*)Cout)[(size_t)row * N + col] = v;
      }
    }
}

// XCD-aware swizzle (R9-verified): lin%8 ~ XCD; group blocks sharing an A-panel (same y)
// onto one XCD. qkv: 768 = 8 XCD x (4 y x 24 x); proj: 512 = 8 XCD x (8 y x 8 x).
__global__ __launch_bounds__(256, 3) void gemm_qkv(const u16* __restrict__ q_bf,
                                                   const u16* __restrict__ WqT,
                                                   u16* __restrict__ qh,
                                                   const u16* __restrict__ kv_bf,
                                                   const u16* __restrict__ WkvT,
                                                   u16* __restrict__ kh,
                                                   const float* __restrict__ gamma,
                                                   const float* __restrict__ beta,
                                                   u16* __restrict__ vt) {
  __shared__ __attribute__((aligned(16))) u16 smem[17408];  // 34816 B (As/Bs | LN tiles)
  int lin = blockIdx.x;
  int k = lin & 7, j = lin >> 3;       // XCD k, 96 blocks each
  int by = 4 * k + j / 24;             // y-tile 0..31 (A-panel local to XCD)
  int bx = j % 24;                     // x-tile 0..23
  if (bx < 8)
    gemm_body<128, 128, true, false>(q_bf, WqT, qh, by * 128, bx * 128, D_, D_,
                                     smem, nullptr, nullptr, nullptr);
  else if (bx < 16)
    gemm_body<128, 128, true, false>(kv_bf, WkvT, kh, by * 128, (bx - 8) * 128, D_, D_,
                                     smem, nullptr, nullptr, nullptr);
  else
    gemm_body<128, 128, true, true>(kv_bf, WkvT, nullptr, by * 128,
                                    1024 + (bx - 16) * 128, 0, D_,
                                    smem, gamma, beta, vt);
}

__global__ __launch_bounds__(256, 3) void gemm_proj(const u16* __restrict__ A,
                                                    const u16* __restrict__ BT,
                                                    float* __restrict__ C) {
  __shared__ __attribute__((aligned(16))) u16 smem[(64 + 128) * 32];
  int lin = blockIdx.x;
  int k = lin & 7, j = lin >> 3;       // XCD k, 64 blocks each
  int by = 8 * k + (j >> 3);           // y-tile 0..63 (A-panel local to XCD)
  int bx = j & 7;                      // x-tile 0..7
  gemm_body<64, 128, false, false>(A, BT, C, by * 64, bx * 128, D_, D_,
                                   smem, nullptr, nullptr, nullptr);
}

// ---------------- attention: q64 tiles, grid (32 bh x 32 y) = 1024 blocks ----------------
// EXACT R6/R9-verified inner structure (depth-1 prefetch; depth-2 spills — do not revisit).
// R10: balanced qt map. With 4 blocks/CU co-resident and round-robin CU = lin%256, a CU's
// 4 blocks share y mod 8; qt in {r, 15-r, 16+r, 31-r} makes every CU's iteration sum
// exactly 66 (complementary pairs), vs 52..80 under qt = 31-y. bh->XCD grouping unchanged.
__global__ __launch_bounds__(256, 4) void attn_kernel(const u16* __restrict__ qh,
                                                      const u16* __restrict__ kh_buf,
                                                      const u16* __restrict__ vt,
                                                      float* __restrict__ out0,
                                                      u16* __restrict__ atv_bf) {
  __shared__ __attribute__((aligned(16))) u16 Ks[2][64][68];  // [buf][kv][d] 17408 B
  __shared__ __attribute__((aligned(16))) u16 Vs[2][64][68];  // [buf][d][kv] 17408 B

  int bh = blockIdx.x;          // 0..31
  int y = blockIdx.y;           // 0..31
  int rr = y & 7, kk = y >> 3;
  int qt = (kk == 0) ? rr : (kk == 1) ? (15 - rr) : (kk == 2) ? (16 + rr) : (31 - rr);
  int h = bh & 15, b = bh >> 4;
  int t = threadIdx.x;
  int w = t >> 6, lane = t & 63;
  int l31 = lane & 31, hi = lane >> 5;
  int qs = w & 1, kh = w >> 1;
  int srow = t >> 2;            // staging row 0..63
  int scol = (t & 3) * 16;      // staging col (elements)

  const float C1 = -0.18033688011f;  // -0.125 * log2(e)
  const float C2 = 11.5415603272f;   // 8 * log2(e)

  const u16* gkb = kh_buf + ((size_t)(b * SKV_) + srow) * 1024 + h * 64 + scol;
  const u16* gvb = vt + ((size_t)((b * H_ + h) * 64 + srow)) * 2048 + scol;
  float* Osc = (float*)&Ks[0][0][0];  // epilogue scratch alias: 64*66*4 = 16896 <= 17408

  int q0 = qt * 64;
  int nkv = qt + 1;

  // Q fragments (B-operand): lane q = q0 + qs*32 + l31, k_dim d = c*16 + hi*8 + j
  s16x8 qf[4];
  {
    const u16* qp = qh + (size_t)(b * SQ_ + q0 + qs * 32 + l31) * D_ + h * 64 + hi * 8;
#pragma unroll
    for (int c = 0; c < 4; c++) qf[c] = *(const s16x8*)(qp + c * 16);
  }

  f32x16 oacc[2] = {};  // partial O (this wave's k-half): [dt] 32q x 32d

  uint4 kr0 = *(const uint4*)gkb, kr1 = *(const uint4*)(gkb + 8);
  uint4 vr0 = *(const uint4*)gvb, vr1 = *(const uint4*)(gvb + 8);

  for (int kt = 0; kt < nkv; kt++) {
    int buf = kt & 1;
    *(uint4*)&Ks[buf][srow][scol] = kr0; *(uint4*)&Ks[buf][srow][scol + 8] = kr1;
    *(uint4*)&Vs[buf][srow][scol] = vr0; *(uint4*)&Vs[buf][srow][scol + 8] = vr1;
    __syncthreads();  // also separates kt-2 reads from this kt's writes (dbuf)
    if (kt + 1 < nkv) {
      const u16* gk2 = gkb + (size_t)(kt + 1) * 64 * 1024;
      const u16* gv2 = gvb + (size_t)(kt + 1) * 64;
      kr0 = *(const uint4*)gk2; kr1 = *(const uint4*)(gk2 + 8);
      vr0 = *(const uint4*)gv2; vr1 = *(const uint4*)(gv2 + 8);
    }

    // ---- S^T for this wave's k32 x q32 ----
    // st reg layout: q = l31, k(within k32) = (reg&3) + 8*(reg>>2) + 4*hi
    f32x16 st = {};
#pragma unroll
    for (int c = 0; c < 4; c++) {
      s16x8 kf = *(const s16x8*)&Ks[buf][kh * 32 + l31][c * 16 + hi * 8];
      st = mfma32(kf, qf[c], st);
    }

    // ---- sigmoid (+ causal mask only on the diagonal tile) -> packed bf16 u32s ----
    unsigned u[8];
    if (kt == nkv - 1) {
      int qi = q0 + qs * 32 + l31;
      int kbase = kt * 64 + kh * 32 + 4 * hi;
#pragma unroll
      for (int g = 0; g < 4; g++) {
        float pv4[4];
#pragma unroll
        for (int i = 0; i < 4; i++) {
          float s = st[4 * g + i];
          float e = __builtin_amdgcn_exp2f(s * C1 + C2);
          float p = __builtin_amdgcn_rcpf(1.0f + e);
          pv4[i] = (kbase + 8 * g + i > qi) ? 0.0f : p;
        }
        u[2 * g] = pack2bf(pv4[0], pv4[1]);
        u[2 * g + 1] = pack2bf(pv4[2], pv4[3]);
      }
    } else {
#pragma unroll
      for (int g = 0; g < 4; g++) {
        float pv4[4];
#pragma unroll
        for (int i = 0; i < 4; i++) {
          float s = st[4 * g + i];
          float e = __builtin_amdgcn_exp2f(s * C1 + C2);
          pv4[i] = __builtin_amdgcn_rcpf(1.0f + e);
        }
        u[2 * g] = pack2bf(pv4[0], pv4[1]);
        u[2 * g + 1] = pack2bf(pv4[2], pv4[3]);
      }
    }

    // ---- T12: in-register re-layout to PV A-operand via permlane32_swap (verified) ----
    union { unsigned wd[4]; s16x8 v; } pa0, pa1;
    {
      auto r02 = __builtin_amdgcn_permlane32_swap(u[0], u[2], false, false);
      auto r13 = __builtin_amdgcn_permlane32_swap(u[1], u[3], false, false);
      auto r46 = __builtin_amdgcn_permlane32_swap(u[4], u[6], false, false);
      auto r57 = __builtin_amdgcn_permlane32_swap(u[5], u[7], false, false);
      pa0.wd[0] = r02[0]; pa0.wd[1] = r13[0]; pa0.wd[2] = r02[1]; pa0.wd[3] = r13[1];
      pa1.wd[0] = r46[0]; pa1.wd[1] = r57[0]; pa1.wd[2] = r46[1]; pa1.wd[3] = r57[1];
    }

    // ---- partial O += P V over this k32 (P register-resident) ----
#pragma unroll
    for (int dt = 0; dt < 2; dt++) {
      s16x8 vf0 = *(const s16x8*)&Vs[buf][dt * 32 + l31][kh * 32 + hi * 8];
      oacc[dt] = mfma32(pa0.v, vf0, oacc[dt]);
      s16x8 vf1 = *(const s16x8*)&Vs[buf][dt * 32 + l31][kh * 32 + 16 + hi * 8];
      oacc[dt] = mfma32(pa1.v, vf1, oacc[dt]);
    }
  }

  // ---- epilogue: reduce the two k-halves via LDS scratch, then store ----
  __syncthreads();  // all K/V reads done; Ks space reusable as Osc
  if (kh == 1) {
#pragma unroll
    for (int dt = 0; dt < 2; dt++)
#pragma unroll
      for (int reg = 0; reg < 16; reg++) {
        int ql = (reg & 3) + 8 * (reg >> 2) + 4 * hi;
        Osc[(qs * 32 + ql) * 66 + dt * 32 + l31] = oacc[dt][reg];
      }
  }
  __syncthreads();
  if (kh == 0) {
#pragma unroll
    for (int dt = 0; dt < 2; dt++)
#pragma unroll
      for (int reg = 0; reg < 16; reg++) {
        int ql = (reg & 3) + 8 * (reg >> 2) + 4 * hi;
        float v = oacc[dt][reg] + Osc[(qs * 32 + ql) * 66 + dt * 32 + l31];
        int row = q0 + qs * 32 + ql;
        int col = h * 64 + dt * 32 + l31;
        size_t idx = (size_t)(b * SQ_ + row) * D_ + col;
        out0[idx] = v;
        atv_bf[idx] = f2bf(v);
      }
  }
}

extern "C" void kernel_launch(void* const* d_in, const int* in_sizes, int n_in,
                              void* d_out, int out_size, void* d_ws, size_t ws_size,
                              hipStream_t stream) {
  const float* q      = (const float*)d_in[0];
  const float* kv     = (const float*)d_in[1];
  const float* Wq     = (const float*)d_in[2];
  const float* Wkv    = (const float*)d_in[3];
  const float* vgamma = (const float*)d_in[4];
  const float* vbeta  = (const float*)d_in[5];
  const float* Wproj  = (const float*)d_in[6];
  float* out0 = (float*)d_out;
  float* out1 = out0 + (size_t)B_ * SQ_ * D_;

  char* p = (char*)d_ws;
  u16* q_bf  = (u16*)p; p += (size_t)B_ * SQ_ * D_ * 2;
  u16* kv_bf = (u16*)p; p += (size_t)B_ * SKV_ * D_ * 2;
  u16* WqT   = (u16*)p; p += (size_t)D_ * D_ * 2;
  u16* WkvT  = (u16*)p; p += (size_t)2 * D_ * D_ * 2;
  u16* WprT  = (u16*)p; p += (size_t)D_ * D_ * 2;
  u16* qh    = (u16*)p; p += (size_t)B_ * SQ_ * D_ * 2;
  u16* kh    = (u16*)p; p += (size_t)B_ * SKV_ * D_ * 2;
  u16* vt    = (u16*)p; p += (size_t)B_ * H_ * HD_ * SKV_ * 2;
  u16* atv   = (u16*)p; p += (size_t)B_ * SQ_ * D_ * 2;

  prep_kernel<<<dim3(12288), 256, 0, stream>>>(q, q_bf, kv, kv_bf, Wq, WqT, Wkv, WkvT, Wproj, WprT);

  gemm_qkv<<<dim3(768), 256, 0, stream>>>(q_bf, WqT, qh, kv_bf, WkvT, kh, vgamma, vbeta, vt);

  attn_kernel<<<dim3(32, 32), 256, 0, stream>>>(qh, kh, vt, out0, atv);

  gemm_proj<<<dim3(512), 256, 0, stream>>>(atv, WprT, out1);
}

// Round 11
// 188.463 us; speedup vs baseline: 1.0055x; 1.0055x over previous
//
#include <hip/hip_runtime.h>
#include <hip/hip_bf16.h>

#define B_ 2
#define SQ_ 2048
#define SKV_ 2048
#define D_ 1024
#define H_ 16
#define HD_ 64

typedef unsigned short u16;
typedef float f32x4 __attribute__((ext_vector_type(4)));
typedef float f32x16 __attribute__((ext_vector_type(16)));
typedef short s16x8 __attribute__((ext_vector_type(8)));

__device__ __forceinline__ u16 f2bf(float f) {
  union { float f; unsigned u; } v; v.f = f;
  return (u16)((v.u + 0x7FFFu + ((v.u >> 16) & 1u)) >> 16);
}
__device__ __forceinline__ float bf2f(u16 h) {
  union { unsigned u; float f; } v; v.u = ((unsigned)h) << 16;
  return v.f;
}
// pack bf16(s1)<<16 | bf16(s0), round-half-up: 2 adds + 1 v_perm
__device__ __forceinline__ unsigned pack2bf(float s0, float s1) {
  union { float f; unsigned u; } a, b; a.f = s0; b.f = s1;
  return __builtin_amdgcn_perm(b.u + 0x8000u, a.u + 0x8000u, 0x07060302u);
}
__device__ __forceinline__ f32x4 mfma16(s16x8 a, s16x8 b, f32x4 c) {
  return __builtin_amdgcn_mfma_f32_16x16x32_bf16(a, b, c, 0, 0, 0);
}
__device__ __forceinline__ f32x16 mfma32(s16x8 a, s16x8 b, f32x16 c) {
  return __builtin_amdgcn_mfma_f32_32x32x16_bf16(a, b, c, 0, 0, 0);
}
// async 16B/lane global -> LDS (dest = wave-uniform base + lane*16)
__device__ __forceinline__ void async16(const u16* g, u16* l) {
  __builtin_amdgcn_global_load_lds(
      (const __attribute__((address_space(1))) unsigned int*)g,
      (__attribute__((address_space(3))) unsigned int*)l, 16, 0, 0);
}

// ---------------- fused prep: cast q, cast kv, transpose 3 weights ----------------
__device__ __forceinline__ void tr_tile(const float* __restrict__ in, u16* __restrict__ out,
                                        int R, int C, int cx, int ry, int t) {
  __shared__ u16 tile[32][33];
  int tx = t & 31, ty = t >> 5;
  int c0 = cx * 32, r0 = ry * 32;
#pragma unroll
  for (int i = 0; i < 4; i++)
    tile[ty + i * 8][tx] = f2bf(in[(size_t)(r0 + ty + i * 8) * C + c0 + tx]);
  __syncthreads();
#pragma unroll
  for (int i = 0; i < 4; i++)
    out[(size_t)(c0 + ty + i * 8) * R + r0 + tx] = tile[tx][ty + i * 8];
}

__device__ __forceinline__ void cast4(const float* __restrict__ in, u16* __restrict__ out,
                                      int i) {
  float4 f = *(const float4*)(in + i);
  ushort4 o;
  o.x = f2bf(f.x); o.y = f2bf(f.y); o.z = f2bf(f.z); o.w = f2bf(f.w);
  *(ushort4*)(out + i) = o;
}

__global__ __launch_bounds__(256) void prep_kernel(
    const float* __restrict__ q, u16* __restrict__ q_bf,
    const float* __restrict__ kv, u16* __restrict__ kv_bf,
    const float* __restrict__ Wq, u16* __restrict__ WqT,
    const float* __restrict__ Wkv, u16* __restrict__ WkvT,
    const float* __restrict__ Wproj, u16* __restrict__ WprT) {
  int bid = blockIdx.x, t = threadIdx.x;
  if (bid < 4096) {
    cast4(q, q_bf, bid * 1024 + t * 4);
  } else if (bid < 8192) {
    cast4(kv, kv_bf, (bid - 4096) * 1024 + t * 4);
  } else if (bid < 9216) {
    int b2 = bid - 8192;
    tr_tile(Wq, WqT, 1024, 1024, b2 & 31, b2 >> 5, t);
  } else if (bid < 11264) {
    int b2 = bid - 9216;
    tr_tile(Wkv, WkvT, 1024, 2048, b2 & 63, b2 >> 6, t);
  } else {
    int b2 = bid - 11264;
    tr_tile(Wproj, WprT, 1024, 1024, b2 & 31, b2 >> 5, t);
  }
}

// ------- m97-style GEMM body: C(BMxBN) = A(BM x K) * BT(BN x K)^T -------
// R10 (kept for verification): T2 XOR-swizzle on the As/Bs 16B slots (rule #21): global
// source quad pre-swizzled (gcol), fragment read uses rq = quad ^ (l16&3) (per-lane
// const). 8-way -> 4-way LDS read conflicts. LNV=true: fused LayerNorm + transpose.
template <int BM, int BN, bool OUT_BF16, bool LNV>
__device__ __forceinline__ void gemm_body(const u16* __restrict__ A,
                                          const u16* __restrict__ BT,
                                          void* __restrict__ Cout,
                                          int m0, int n0, int N, int K,
                                          u16* __restrict__ smem,
                                          const float* __restrict__ gamma,
                                          const float* __restrict__ beta,
                                          u16* __restrict__ vt) {
  u16* As = smem;             // [BM][32]
  u16* Bs = smem + BM * 32;   // [BN][32]
  constexpr int AM = BM / 32, AN = BN / 32;
  int t = threadIdx.x, w = t >> 6, lane = t & 63;
  int l16 = lane & 15, quad = lane >> 4;
  int mw = (w >> 1) * (BM / 2), nw = (w & 1) * (BN / 2);
  int grow = w * 16 + (lane >> 2);
  int gcol = ((lane & 3) ^ ((lane >> 2) & 3)) * 8;  // pre-swizzled source quad
  int rq = quad ^ (l16 & 3);                        // swizzled read quad (per-lane const)

  f32x4 acc[AM][AN] = {};

  for (int kt = 0; kt < K; kt += 32) {
    __syncthreads();
#pragma unroll
    for (int j = 0; j < BM / 64; j++)
      async16(A + (size_t)(m0 + j * 64 + grow) * K + kt + gcol, &As[(j * 64 + w * 16) * 32]);
#pragma unroll
    for (int j = 0; j < BN / 64; j++)
      async16(BT + (size_t)(n0 + j * 64 + grow) * K + kt + gcol, &Bs[(j * 64 + w * 16) * 32]);
    __syncthreads();
    s16x8 af[AM], bf[AN];
#pragma unroll
    for (int i = 0; i < AM; i++) af[i] = *(const s16x8*)&As[(mw + i * 16 + l16) * 32 + rq * 8];
#pragma unroll
    for (int j = 0; j < AN; j++) bf[j] = *(const s16x8*)&Bs[(nw + j * 16 + l16) * 32 + rq * 8];
#pragma unroll
    for (int i = 0; i < AM; i++)
#pragma unroll
      for (int j = 0; j < AN; j++)
        acc[i][j] = mfma16(af[i], bf[j], acc[i][j]);
  }

  if constexpr (LNV) {
    // ---- fused LayerNorm over head dim + transpose to vt[b,h,d,s] ----
    __syncthreads();  // all waves done reading As/Bs; smem reusable as tiles
    u16* tile = smem + w * 4352;  // per-wave [64][68] u16 (8704 B), private
    int h = (n0 - 1024 + nw) >> 6;   // global head 0..15
    int b_ = m0 >> 11;
    int s0 = (m0 & 2047) + mw;
    float g4[4], be4[4];
#pragma unroll
    for (int j = 0; j < 4; j++) { g4[j] = gamma[j * 16 + l16]; be4[j] = beta[j * 16 + l16]; }
#pragma unroll
    for (int i = 0; i < 4; i++) {
      float mu[4], inv[4];
#pragma unroll
      for (int r = 0; r < 4; r++) {
        float x0 = acc[i][0][r], x1 = acc[i][1][r], x2 = acc[i][2][r], x3 = acc[i][3][r];
        float rs = x0 + x1 + x2 + x3;
        rs += __shfl_xor(rs, 1); rs += __shfl_xor(rs, 2);
        rs += __shfl_xor(rs, 4); rs += __shfl_xor(rs, 8);
        float m = rs * 0.015625f;
        float d0 = x0 - m, d1 = x1 - m, d2 = x2 - m, d3 = x3 - m;
        float vs = d0 * d0 + d1 * d1 + d2 * d2 + d3 * d3;
        vs += __shfl_xor(vs, 1); vs += __shfl_xor(vs, 2);
        vs += __shfl_xor(vs, 4); vs += __shfl_xor(vs, 8);
        mu[r] = m;
        inv[r] = rsqrtf(vs * 0.015625f + 1e-5f);
      }
#pragma unroll
      for (int j = 0; j < 4; j++) {
        ushort4 o;
        o.x = f2bf((acc[i][j][0] - mu[0]) * inv[0] * g4[j] + be4[j]);
        o.y = f2bf((acc[i][j][1] - mu[1]) * inv[1] * g4[j] + be4[j]);
        o.z = f2bf((acc[i][j][2] - mu[2]) * inv[2] * g4[j] + be4[j]);
        o.w = f2bf((acc[i][j][3] - mu[3]) * inv[3] * g4[j] + be4[j]);
        // tile[d = j*16+l16][s4 = i*16+quad*4]: 8B-aligned (stride 136 B)
        *(ushort4*)&tile[(size_t)(j * 16 + l16) * 68 + i * 16 + quad * 4] = o;
      }
    }
    // readout: lane-private region of this wave's tile (compiler orders via lgkmcnt)
    size_t vbase = ((size_t)((b_ * 16 + h) * 64)) * 2048 + s0;
#pragma unroll
    for (int p = 0; p < 4; p++) {
      int d = p * 16 + (lane >> 2);
      int sc = (lane & 3) * 16;
      uint2 a0 = *(uint2*)&tile[(size_t)d * 68 + sc];
      uint2 a1 = *(uint2*)&tile[(size_t)d * 68 + sc + 4];
      uint2 a2 = *(uint2*)&tile[(size_t)d * 68 + sc + 8];
      uint2 a3 = *(uint2*)&tile[(size_t)d * 68 + sc + 12];
      uint4 w0; w0.x = a0.x; w0.y = a0.y; w0.z = a1.x; w0.w = a1.y;
      uint4 w1; w1.x = a2.x; w1.y = a2.y; w1.z = a3.x; w1.w = a3.y;
      *(uint4*)(vt + vbase + (size_t)d * 2048 + sc) = w0;
      *(uint4*)(vt + vbase + (size_t)d * 2048 + sc + 8) = w1;
    }
    return;
  }

#pragma unroll
  for (int i = 0; i < AM; i++)
#pragma unroll
    for (int j = 0; j < AN; j++) {
      int col = n0 + nw + j * 16 + l16;
#pragma unroll
      for (int r = 0; r < 4; r++) {
        int row = m0 + mw + i * 16 + quad * 4 + r;
        float v = acc[i][j][r];
        if (OUT_BF16)
          ((u16*)Cout)[(size_t)row * N + col] = f2bf(v);
        else
          ((float*)Cout)[(size_t)row * N + col] = v;
      }
    }
}

// XCD-aware swizzle (R9-verified): lin%8 ~ XCD; group blocks sharing an A-panel (same y)
// onto one XCD. qkv: 768 = 8 XCD x (4 y x 24 x); proj: 512 = 8 XCD x (8 y x 8 x).
__global__ __launch_bounds__(256, 3) void gemm_qkv(const u16* __restrict__ q_bf,
                                                   const u16* __restrict__ WqT,
                                                   u16* __restrict__ qh,
                                                   const u16* __restrict__ kv_bf,
                                                   const u16* __restrict__ WkvT,
                                                   u16* __restrict__ kh,
                                                   const float* __restrict__ gamma,
                                                   const float* __restrict__ beta,
                                                   u16* __restrict__ vt) {
  __shared__ __attribute__((aligned(16))) u16 smem[17408];  // 34816 B (As/Bs | LN tiles)
  int lin = blockIdx.x;
  int k = lin & 7, j = lin >> 3;       // XCD k, 96 blocks each
  int by = 4 * k + j / 24;             // y-tile 0..31 (A-panel local to XCD)
  int bx = j % 24;                     // x-tile 0..23
  if (bx < 8)
    gemm_body<128, 128, true, false>(q_bf, WqT, qh, by * 128, bx * 128, D_, D_,
                                     smem, nullptr, nullptr, nullptr);
  else if (bx < 16)
    gemm_body<128, 128, true, false>(kv_bf, WkvT, kh, by * 128, (bx - 8) * 128, D_, D_,
                                     smem, nullptr, nullptr, nullptr);
  else
    gemm_body<128, 128, true, true>(kv_bf, WkvT, nullptr, by * 128,
                                    1024 + (bx - 16) * 128, 0, D_,
                                    smem, gamma, beta, vt);
}

__global__ __launch_bounds__(256, 3) void gemm_proj(const u16* __restrict__ A,
                                                    const u16* __restrict__ BT,
                                                    float* __restrict__ C) {
  __shared__ __attribute__((aligned(16))) u16 smem[(64 + 128) * 32];
  int lin = blockIdx.x;
  int k = lin & 7, j = lin >> 3;       // XCD k, 64 blocks each
  int by = 8 * k + (j >> 3);           // y-tile 0..63 (A-panel local to XCD)
  int bx = j & 7;                      // x-tile 0..7
  gemm_body<64, 128, false, false>(A, BT, C, by * 64, bx * 128, D_, D_,
                                   smem, nullptr, nullptr, nullptr);
}

// ---------------- attention: q64 tiles, grid (32 bh x 32 qt) = 1024 blocks ----------------
// R6/R9-verified structure; qt = 31 - y REVERTED (R10's "balanced" map cost +1.8 us:
// wrong CU model + lost LPT). NEW (R11): T5 s_setprio(1) around QK and PV MFMA clusters —
// 4 independent blocks/CU give wave role diversity (m191: +4-7% on attn; null only for
// lockstep grids). Depth-2 prefetch attempts spill (R7/R8) — do not revisit.
__global__ __launch_bounds__(256, 4) void attn_kernel(const u16* __restrict__ qh,
                                                      const u16* __restrict__ kh_buf,
                                                      const u16* __restrict__ vt,
                                                      float* __restrict__ out0,
                                                      u16* __restrict__ atv_bf) {
  __shared__ __attribute__((aligned(16))) u16 Ks[2][64][68];  // [buf][kv][d] 17408 B
  __shared__ __attribute__((aligned(16))) u16 Vs[2][64][68];  // [buf][d][kv] 17408 B

  int bh = blockIdx.x;          // 0..31
  int qt = 31 - blockIdx.y;     // descending work size (LPT; verified)
  int h = bh & 15, b = bh >> 4;
  int t = threadIdx.x;
  int w = t >> 6, lane = t & 63;
  int l31 = lane & 31, hi = lane >> 5;
  int qs = w & 1, kh = w >> 1;
  int srow = t >> 2;            // staging row 0..63
  int scol = (t & 3) * 16;      // staging col (elements)

  const float C1 = -0.18033688011f;  // -0.125 * log2(e)
  const float C2 = 11.5415603272f;   // 8 * log2(e)

  const u16* gkb = kh_buf + ((size_t)(b * SKV_) + srow) * 1024 + h * 64 + scol;
  const u16* gvb = vt + ((size_t)((b * H_ + h) * 64 + srow)) * 2048 + scol;
  float* Osc = (float*)&Ks[0][0][0];  // epilogue scratch alias: 64*66*4 = 16896 <= 17408

  int q0 = qt * 64;
  int nkv = qt + 1;

  // Q fragments (B-operand): lane q = q0 + qs*32 + l31, k_dim d = c*16 + hi*8 + j
  s16x8 qf[4];
  {
    const u16* qp = qh + (size_t)(b * SQ_ + q0 + qs * 32 + l31) * D_ + h * 64 + hi * 8;
#pragma unroll
    for (int c = 0; c < 4; c++) qf[c] = *(const s16x8*)(qp + c * 16);
  }

  f32x16 oacc[2] = {};  // partial O (this wave's k-half): [dt] 32q x 32d

  uint4 kr0 = *(const uint4*)gkb, kr1 = *(const uint4*)(gkb + 8);
  uint4 vr0 = *(const uint4*)gvb, vr1 = *(const uint4*)(gvb + 8);

  for (int kt = 0; kt < nkv; kt++) {
    int buf = kt & 1;
    *(uint4*)&Ks[buf][srow][scol] = kr0; *(uint4*)&Ks[buf][srow][scol + 8] = kr1;
    *(uint4*)&Vs[buf][srow][scol] = vr0; *(uint4*)&Vs[buf][srow][scol + 8] = vr1;
    __syncthreads();  // also separates kt-2 reads from this kt's writes (dbuf)
    if (kt + 1 < nkv) {
      const u16* gk2 = gkb + (size_t)(kt + 1) * 64 * 1024;
      const u16* gv2 = gvb + (size_t)(kt + 1) * 64;
      kr0 = *(const uint4*)gk2; kr1 = *(const uint4*)(gk2 + 8);
      vr0 = *(const uint4*)gv2; vr1 = *(const uint4*)(gv2 + 8);
    }

    // ---- S^T for this wave's k32 x q32 ----
    // st reg layout: q = l31, k(within k32) = (reg&3) + 8*(reg>>2) + 4*hi
    f32x16 st = {};
    __builtin_amdgcn_s_setprio(1);
#pragma unroll
    for (int c = 0; c < 4; c++) {
      s16x8 kf = *(const s16x8*)&Ks[buf][kh * 32 + l31][c * 16 + hi * 8];
      st = mfma32(kf, qf[c], st);
    }
    __builtin_amdgcn_s_setprio(0);

    // ---- sigmoid (+ causal mask only on the diagonal tile) -> packed bf16 u32s ----
    unsigned u[8];
    if (kt == nkv - 1) {
      int qi = q0 + qs * 32 + l31;
      int kbase = kt * 64 + kh * 32 + 4 * hi;
#pragma unroll
      for (int g = 0; g < 4; g++) {
        float pv4[4];
#pragma unroll
        for (int i = 0; i < 4; i++) {
          float s = st[4 * g + i];
          float e = __builtin_amdgcn_exp2f(s * C1 + C2);
          float p = __builtin_amdgcn_rcpf(1.0f + e);
          pv4[i] = (kbase + 8 * g + i > qi) ? 0.0f : p;
        }
        u[2 * g] = pack2bf(pv4[0], pv4[1]);
        u[2 * g + 1] = pack2bf(pv4[2], pv4[3]);
      }
    } else {
#pragma unroll
      for (int g = 0; g < 4; g++) {
        float pv4[4];
#pragma unroll
        for (int i = 0; i < 4; i++) {
          float s = st[4 * g + i];
          float e = __builtin_amdgcn_exp2f(s * C1 + C2);
          pv4[i] = __builtin_amdgcn_rcpf(1.0f + e);
        }
        u[2 * g] = pack2bf(pv4[0], pv4[1]);
        u[2 * g + 1] = pack2bf(pv4[2], pv4[3]);
      }
    }

    // ---- T12: in-register re-layout to PV A-operand via permlane32_swap (verified) ----
    union { unsigned wd[4]; s16x8 v; } pa0, pa1;
    {
      auto r02 = __builtin_amdgcn_permlane32_swap(u[0], u[2], false, false);
      auto r13 = __builtin_amdgcn_permlane32_swap(u[1], u[3], false, false);
      auto r46 = __builtin_amdgcn_permlane32_swap(u[4], u[6], false, false);
      auto r57 = __builtin_amdgcn_permlane32_swap(u[5], u[7], false, false);
      pa0.wd[0] = r02[0]; pa0.wd[1] = r13[0]; pa0.wd[2] = r02[1]; pa0.wd[3] = r13[1];
      pa1.wd[0] = r46[0]; pa1.wd[1] = r57[0]; pa1.wd[2] = r46[1]; pa1.wd[3] = r57[1];
    }

    // ---- partial O += P V over this k32 (P register-resident) ----
    __builtin_amdgcn_s_setprio(1);
#pragma unroll
    for (int dt = 0; dt < 2; dt++) {
      s16x8 vf0 = *(const s16x8*)&Vs[buf][dt * 32 + l31][kh * 32 + hi * 8];
      oacc[dt] = mfma32(pa0.v, vf0, oacc[dt]);
      s16x8 vf1 = *(const s16x8*)&Vs[buf][dt * 32 + l31][kh * 32 + 16 + hi * 8];
      oacc[dt] = mfma32(pa1.v, vf1, oacc[dt]);
    }
    __builtin_amdgcn_s_setprio(0);
  }

  // ---- epilogue: reduce the two k-halves via LDS scratch, then store ----
  __syncthreads();  // all K/V reads done; Ks space reusable as Osc
  if (kh == 1) {
#pragma unroll
    for (int dt = 0; dt < 2; dt++)
#pragma unroll
      for (int reg = 0; reg < 16; reg++) {
        int ql = (reg & 3) + 8 * (reg >> 2) + 4 * hi;
        Osc[(qs * 32 + ql) * 66 + dt * 32 + l31] = oacc[dt][reg];
      }
  }
  __syncthreads();
  if (kh == 0) {
#pragma unroll
    for (int dt = 0; dt < 2; dt++)
#pragma unroll
      for (int reg = 0; reg < 16; reg++) {
        int ql = (reg & 3) + 8 * (reg >> 2) + 4 * hi;
        float v = oacc[dt][reg] + Osc[(qs * 32 + ql) * 66 + dt * 32 + l31];
        int row = q0 + qs * 32 + ql;
        int col = h * 64 + dt * 32 + l31;
        size_t idx = (size_t)(b * SQ_ + row) * D_ + col;
        out0[idx] = v;
        atv_bf[idx] = f2bf(v);
      }
  }
}

extern "C" void kernel_launch(void* const* d_in, const int* in_sizes, int n_in,
                              void* d_out, int out_size, void* d_ws, size_t ws_size,
                              hipStream_t stream) {
  const float* q      = (const float*)d_in[0];
  const float* kv     = (const float*)d_in[1];
  const float* Wq     = (const float*)d_in[2];
  const float* Wkv    = (const float*)d_in[3];
  const float* vgamma = (const float*)d_in[4];
  const float* vbeta  = (const float*)d_in[5];
  const float* Wproj  = (const float*)d_in[6];
  float* out0 = (float*)d_out;
  float* out1 = out0 + (size_t)B_ * SQ_ * D_;

  char* p = (char*)d_ws;
  u16* q_bf  = (u16*)p; p += (size_t)B_ * SQ_ * D_ * 2;
  u16* kv_bf = (u16*)p; p += (size_t)B_ * SKV_ * D_ * 2;
  u16* WqT   = (u16*)p; p += (size_t)D_ * D_ * 2;
  u16* WkvT  = (u16*)p; p += (size_t)2 * D_ * D_ * 2;
  u16* WprT  = (u16*)p; p += (size_t)D_ * D_ * 2;
  u16* qh    = (u16*)p; p += (size_t)B_ * SQ_ * D_ * 2;
  u16* kh    = (u16*)p; p += (size_t)B_ * SKV_ * D_ * 2;
  u16* vt    = (u16*)p; p += (size_t)B_ * H_ * HD_ * SKV_ * 2;
  u16* atv   = (u16*)p; p += (size_t)B_ * SQ_ * D_ * 2;

  prep_kernel<<<dim3(12288), 256, 0, stream>>>(q, q_bf, kv, kv_bf, Wq, WqT, Wkv, WkvT, Wproj, WprT);

  gemm_qkv<<<dim3(768), 256, 0, stream>>>(q_bf, WqT, qh, kv_bf, WkvT, kh, vgamma, vbeta, vt);

  attn_kernel<<<dim3(32, 32), 256, 0, stream>>>(qh, kh, vt, out0, atv);

  gemm_proj<<<dim3(512), 256, 0, stream>>>(atv, WprT, out1);
}

// Round 13
// 185.907 us; speedup vs baseline: 1.0193x; 1.0137x over previous
//
#include <hip/hip_runtime.h>
#include <hip/hip_bf16.h>

#define B_ 2
#define SQ_ 2048
#define SKV_ 2048
#define D_ 1024
#define H_ 16
#define HD_ 64

typedef unsigned short u16;
typedef float f32x4 __attribute__((ext_vector_type(4)));
typedef float f32x16 __attribute__((ext_vector_type(16)));
typedef short s16x8 __attribute__((ext_vector_type(8)));

__device__ __forceinline__ u16 f2bf(float f) {
  union { float f; unsigned u; } v; v.f = f;
  return (u16)((v.u + 0x7FFFu + ((v.u >> 16) & 1u)) >> 16);
}
__device__ __forceinline__ float bf2f(u16 h) {
  union { unsigned u; float f; } v; v.u = ((unsigned)h) << 16;
  return v.f;
}
// pack bf16(s1)<<16 | bf16(s0), round-half-up: 2 adds + 1 v_perm
__device__ __forceinline__ unsigned pack2bf(float s0, float s1) {
  union { float f; unsigned u; } a, b; a.f = s0; b.f = s1;
  return __builtin_amdgcn_perm(b.u + 0x8000u, a.u + 0x8000u, 0x07060302u);
}
__device__ __forceinline__ f32x4 mfma16(s16x8 a, s16x8 b, f32x4 c) {
  return __builtin_amdgcn_mfma_f32_16x16x32_bf16(a, b, c, 0, 0, 0);
}
__device__ __forceinline__ f32x16 mfma32(s16x8 a, s16x8 b, f32x16 c) {
  return __builtin_amdgcn_mfma_f32_32x32x16_bf16(a, b, c, 0, 0, 0);
}
// async 16B/lane global -> LDS (dest = wave-uniform base + lane*16)
__device__ __forceinline__ void async16(const u16* g, u16* l) {
  __builtin_amdgcn_global_load_lds(
      (const __attribute__((address_space(1))) unsigned int*)g,
      (__attribute__((address_space(3))) unsigned int*)l, 16, 0, 0);
}

// ---------------- fused prep: cast q, cast kv, transpose 3 weights ----------------
__device__ __forceinline__ void tr_tile(const float* __restrict__ in, u16* __restrict__ out,
                                        int R, int C, int cx, int ry, int t) {
  __shared__ u16 tile[32][33];
  int tx = t & 31, ty = t >> 5;
  int c0 = cx * 32, r0 = ry * 32;
#pragma unroll
  for (int i = 0; i < 4; i++)
    tile[ty + i * 8][tx] = f2bf(in[(size_t)(r0 + ty + i * 8) * C + c0 + tx]);
  __syncthreads();
#pragma unroll
  for (int i = 0; i < 4; i++)
    out[(size_t)(c0 + ty + i * 8) * R + r0 + tx] = tile[tx][ty + i * 8];
}

__device__ __forceinline__ void cast4(const float* __restrict__ in, u16* __restrict__ out,
                                      int i) {
  float4 f = *(const float4*)(in + i);
  ushort4 o;
  o.x = f2bf(f.x); o.y = f2bf(f.y); o.z = f2bf(f.z); o.w = f2bf(f.w);
  *(ushort4*)(out + i) = o;
}

__global__ __launch_bounds__(256) void prep_kernel(
    const float* __restrict__ q, u16* __restrict__ q_bf,
    const float* __restrict__ kv, u16* __restrict__ kv_bf,
    const float* __restrict__ Wq, u16* __restrict__ WqT,
    const float* __restrict__ Wkv, u16* __restrict__ WkvT,
    const float* __restrict__ Wproj, u16* __restrict__ WprT) {
  int bid = blockIdx.x, t = threadIdx.x;
  if (bid < 4096) {
    cast4(q, q_bf, bid * 1024 + t * 4);
  } else if (bid < 8192) {
    cast4(kv, kv_bf, (bid - 4096) * 1024 + t * 4);
  } else if (bid < 9216) {
    int b2 = bid - 8192;
    tr_tile(Wq, WqT, 1024, 1024, b2 & 31, b2 >> 5, t);
  } else if (bid < 11264) {
    int b2 = bid - 9216;
    tr_tile(Wkv, WkvT, 1024, 2048, b2 & 63, b2 >> 6, t);
  } else {
    int b2 = bid - 11264;
    tr_tile(Wproj, WprT, 1024, 1024, b2 & 31, b2 >> 5, t);
  }
}

// ------- m97-style GEMM body: C(BMxBN) = A(BM x K) * BT(BN x K)^T -------
// LNV=true (kv V-half): instead of writing C, LayerNorm rows over the 64-wide head
// owned by each wave (4 adds + 4 shfl_xor per row within 16-lane quads), transpose
// through a per-wave-private LDS tile (no barrier needed), store to vt[b,h,d,s].
template <int BM, int BN, bool OUT_BF16, bool LNV>
__device__ __forceinline__ void gemm_body(const u16* __restrict__ A,
                                          const u16* __restrict__ BT,
                                          void* __restrict__ Cout,
                                          int m0, int n0, int N, int K,
                                          u16* __restrict__ smem,
                                          const float* __restrict__ gamma,
                                          const float* __restrict__ beta,
                                          u16* __restrict__ vt) {
  u16* As = smem;             // [BM][32]
  u16* Bs = smem + BM * 32;   // [BN][32]
  constexpr int AM = BM / 32, AN = BN / 32;
  int t = threadIdx.x, w = t >> 6, lane = t & 63;
  int l16 = lane & 15, quad = lane >> 4;
  int mw = (w >> 1) * (BM / 2), nw = (w & 1) * (BN / 2);
  int grow = w * 16 + (lane >> 2);
  int gcol = (lane & 3) * 8;

  f32x4 acc[AM][AN] = {};

  for (int kt = 0; kt < K; kt += 32) {
    __syncthreads();
#pragma unroll
    for (int j = 0; j < BM / 64; j++)
      async16(A + (size_t)(m0 + j * 64 + grow) * K + kt + gcol, &As[(j * 64 + w * 16) * 32]);
#pragma unroll
    for (int j = 0; j < BN / 64; j++)
      async16(BT + (size_t)(n0 + j * 64 + grow) * K + kt + gcol, &Bs[(j * 64 + w * 16) * 32]);
    __syncthreads();
    s16x8 af[AM], bf[AN];
#pragma unroll
    for (int i = 0; i < AM; i++) af[i] = *(const s16x8*)&As[(mw + i * 16 + l16) * 32 + quad * 8];
#pragma unroll
    for (int j = 0; j < AN; j++) bf[j] = *(const s16x8*)&Bs[(nw + j * 16 + l16) * 32 + quad * 8];
#pragma unroll
    for (int i = 0; i < AM; i++)
#pragma unroll
      for (int j = 0; j < AN; j++)
        acc[i][j] = mfma16(af[i], bf[j], acc[i][j]);
  }

  if constexpr (LNV) {
    // ---- fused LayerNorm over head dim + transpose to vt[b,h,d,s] ----
    __syncthreads();  // all waves done reading As/Bs; smem reusable as tiles
    u16* tile = smem + w * 4352;  // per-wave [64][68] u16 (8704 B), private
    int h = (n0 - 1024 + nw) >> 6;   // global head 0..15
    int b_ = m0 >> 11;
    int s0 = (m0 & 2047) + mw;
    float g4[4], be4[4];
#pragma unroll
    for (int j = 0; j < 4; j++) { g4[j] = gamma[j * 16 + l16]; be4[j] = beta[j * 16 + l16]; }
#pragma unroll
    for (int i = 0; i < 4; i++) {
      float mu[4], inv[4];
#pragma unroll
      for (int r = 0; r < 4; r++) {
        float x0 = acc[i][0][r], x1 = acc[i][1][r], x2 = acc[i][2][r], x3 = acc[i][3][r];
        float rs = x0 + x1 + x2 + x3;
        rs += __shfl_xor(rs, 1); rs += __shfl_xor(rs, 2);
        rs += __shfl_xor(rs, 4); rs += __shfl_xor(rs, 8);
        float m = rs * 0.015625f;
        float d0 = x0 - m, d1 = x1 - m, d2 = x2 - m, d3 = x3 - m;
        float vs = d0 * d0 + d1 * d1 + d2 * d2 + d3 * d3;
        vs += __shfl_xor(vs, 1); vs += __shfl_xor(vs, 2);
        vs += __shfl_xor(vs, 4); vs += __shfl_xor(vs, 8);
        mu[r] = m;
        inv[r] = rsqrtf(vs * 0.015625f + 1e-5f);
      }
#pragma unroll
      for (int j = 0; j < 4; j++) {
        ushort4 o;
        o.x = f2bf((acc[i][j][0] - mu[0]) * inv[0] * g4[j] + be4[j]);
        o.y = f2bf((acc[i][j][1] - mu[1]) * inv[1] * g4[j] + be4[j]);
        o.z = f2bf((acc[i][j][2] - mu[2]) * inv[2] * g4[j] + be4[j]);
        o.w = f2bf((acc[i][j][3] - mu[3]) * inv[3] * g4[j] + be4[j]);
        // tile[d = j*16+l16][s4 = i*16+quad*4]: 8B-aligned (stride 136 B)
        *(ushort4*)&tile[(size_t)(j * 16 + l16) * 68 + i * 16 + quad * 4] = o;
      }
    }
    // readout: lane-private region of this wave's tile (compiler orders via lgkmcnt)
    size_t vbase = ((size_t)((b_ * 16 + h) * 64)) * 2048 + s0;
#pragma unroll
    for (int p = 0; p < 4; p++) {
      int d = p * 16 + (lane >> 2);
      int sc = (lane & 3) * 16;
      uint2 a0 = *(uint2*)&tile[(size_t)d * 68 + sc];
      uint2 a1 = *(uint2*)&tile[(size_t)d * 68 + sc + 4];
      uint2 a2 = *(uint2*)&tile[(size_t)d * 68 + sc + 8];
      uint2 a3 = *(uint2*)&tile[(size_t)d * 68 + sc + 12];
      uint4 w0; w0.x = a0.x; w0.y = a0.y; w0.z = a1.x; w0.w = a1.y;
      uint4 w1; w1.x = a2.x; w1.y = a2.y; w1.z = a3.x; w1.w = a3.y;
      *(uint4*)(vt + vbase + (size_t)d * 2048 + sc) = w0;
      *(uint4*)(vt + vbase + (size_t)d * 2048 + sc + 8) = w1;
    }
    return;
  }

#pragma unroll
  for (int i = 0; i < AM; i++)
#pragma unroll
    for (int j = 0; j < AN; j++) {
      int col = n0 + nw + j * 16 + l16;
#pragma unroll
      for (int r = 0; r < 4; r++) {
        int row = m0 + mw + i * 16 + quad * 4 + r;
        float v = acc[i][j][r];
        if (OUT_BF16)
          ((u16*)Cout)[(size_t)row * N + col] = f2bf(v);
        else
          ((float*)Cout)[(size_t)row * N + col] = v;
      }
    }
}

// XCD-aware swizzle (R9-verified): lin%8 ~ XCD; group blocks sharing an A-panel (same y)
// onto one XCD. qkv: 768 = 8 XCD x (4 y x 24 x); proj: 512 = 8 XCD x (8 y x 8 x).
__global__ __launch_bounds__(256, 3) void gemm_qkv(const u16* __restrict__ q_bf,
                                                   const u16* __restrict__ WqT,
                                                   u16* __restrict__ qh,
                                                   const u16* __restrict__ kv_bf,
                                                   const u16* __restrict__ WkvT,
                                                   u16* __restrict__ kh,
                                                   const float* __restrict__ gamma,
                                                   const float* __restrict__ beta,
                                                   u16* __restrict__ vt) {
  __shared__ __attribute__((aligned(16))) u16 smem[17408];  // 34816 B (As/Bs | LN tiles)
  int lin = blockIdx.x;
  int k = lin & 7, j = lin >> 3;       // XCD k, 96 blocks each
  int by = 4 * k + j / 24;             // y-tile 0..31 (A-panel local to XCD)
  int bx = j % 24;                     // x-tile 0..23
  if (bx < 8)
    gemm_body<128, 128, true, false>(q_bf, WqT, qh, by * 128, bx * 128, D_, D_,
                                     smem, nullptr, nullptr, nullptr);
  else if (bx < 16)
    gemm_body<128, 128, true, false>(kv_bf, WkvT, kh, by * 128, (bx - 8) * 128, D_, D_,
                                     smem, nullptr, nullptr, nullptr);
  else
    gemm_body<128, 128, true, true>(kv_bf, WkvT, nullptr, by * 128,
                                    1024 + (bx - 16) * 128, 0, D_,
                                    smem, gamma, beta, vt);
}

__global__ __launch_bounds__(256, 3) void gemm_proj(const u16* __restrict__ A,
                                                    const u16* __restrict__ BT,
                                                    float* __restrict__ C) {
  __shared__ __attribute__((aligned(16))) u16 smem[(64 + 128) * 32];
  int lin = blockIdx.x;
  int k = lin & 7, j = lin >> 3;       // XCD k, 64 blocks each
  int by = 8 * k + (j >> 3);           // y-tile 0..63 (A-panel local to XCD)
  int bx = j & 7;                      // x-tile 0..7
  gemm_body<64, 128, false, false>(A, BT, C, by * 64, bx * 128, D_, D_,
                                   smem, nullptr, nullptr, nullptr);
}

// ---------------- attention: q64 tiles, grid (32 bh x 32 qt) = 1024 blocks ----------------
// EXACT R9-verified structure (best total 186.8 us). Depth-1 register prefetch; depth-2
// spills (R7/R8); async-LDS dbuf staging NaN'd (R12) — both dead ends, do not revisit.
// bh%8 keeps each head's K/V on one XCD (L2-local). qt = 31-y (LPT; verified).
__global__ __launch_bounds__(256, 4) void attn_kernel(const u16* __restrict__ qh,
                                                      const u16* __restrict__ kh_buf,
                                                      const u16* __restrict__ vt,
                                                      float* __restrict__ out0,
                                                      u16* __restrict__ atv_bf) {
  __shared__ __attribute__((aligned(16))) u16 Ks[2][64][68];  // [buf][kv][d] 17408 B
  __shared__ __attribute__((aligned(16))) u16 Vs[2][64][68];  // [buf][d][kv] 17408 B

  int bh = blockIdx.x;          // 0..31
  int qt = 31 - blockIdx.y;     // descending work size
  int h = bh & 15, b = bh >> 4;
  int t = threadIdx.x;
  int w = t >> 6, lane = t & 63;
  int l31 = lane & 31, hi = lane >> 5;
  int qs = w & 1, kh = w >> 1;
  int srow = t >> 2;            // staging row 0..63
  int scol = (t & 3) * 16;      // staging col (elements)

  const float C1 = -0.18033688011f;  // -0.125 * log2(e)
  const float C2 = 11.5415603272f;   // 8 * log2(e)

  const u16* gkb = kh_buf + ((size_t)(b * SKV_) + srow) * 1024 + h * 64 + scol;
  const u16* gvb = vt + ((size_t)((b * H_ + h) * 64 + srow)) * 2048 + scol;
  float* Osc = (float*)&Ks[0][0][0];  // epilogue scratch alias: 64*66*4 = 16896 <= 17408

  int q0 = qt * 64;
  int nkv = qt + 1;

  // Q fragments (B-operand): lane q = q0 + qs*32 + l31, k_dim d = c*16 + hi*8 + j
  s16x8 qf[4];
  {
    const u16* qp = qh + (size_t)(b * SQ_ + q0 + qs * 32 + l31) * D_ + h * 64 + hi * 8;
#pragma unroll
    for (int c = 0; c < 4; c++) qf[c] = *(const s16x8*)(qp + c * 16);
  }

  f32x16 oacc[2] = {};  // partial O (this wave's k-half): [dt] 32q x 32d

  uint4 kr0 = *(const uint4*)gkb, kr1 = *(const uint4*)(gkb + 8);
  uint4 vr0 = *(const uint4*)gvb, vr1 = *(const uint4*)(gvb + 8);

  for (int kt = 0; kt < nkv; kt++) {
    int buf = kt & 1;
    *(uint4*)&Ks[buf][srow][scol] = kr0; *(uint4*)&Ks[buf][srow][scol + 8] = kr1;
    *(uint4*)&Vs[buf][srow][scol] = vr0; *(uint4*)&Vs[buf][srow][scol + 8] = vr1;
    __syncthreads();  // also separates kt-2 reads from this kt's writes (dbuf)
    if (kt + 1 < nkv) {
      const u16* gk2 = gkb + (size_t)(kt + 1) * 64 * 1024;
      const u16* gv2 = gvb + (size_t)(kt + 1) * 64;
      kr0 = *(const uint4*)gk2; kr1 = *(const uint4*)(gk2 + 8);
      vr0 = *(const uint4*)gv2; vr1 = *(const uint4*)(gv2 + 8);
    }

    // ---- S^T for this wave's k32 x q32 ----
    // st reg layout: q = l31, k(within k32) = (reg&3) + 8*(reg>>2) + 4*hi
    f32x16 st = {};
#pragma unroll
    for (int c = 0; c < 4; c++) {
      s16x8 kf = *(const s16x8*)&Ks[buf][kh * 32 + l31][c * 16 + hi * 8];
      st = mfma32(kf, qf[c], st);
    }

    // ---- sigmoid (+ causal mask only on the diagonal tile) -> packed bf16 u32s ----
    unsigned u[8];
    if (kt == nkv - 1) {
      int qi = q0 + qs * 32 + l31;
      int kbase = kt * 64 + kh * 32 + 4 * hi;
#pragma unroll
      for (int g = 0; g < 4; g++) {
        float pv4[4];
#pragma unroll
        for (int i = 0; i < 4; i++) {
          float s = st[4 * g + i];
          float e = __builtin_amdgcn_exp2f(s * C1 + C2);
          float p = __builtin_amdgcn_rcpf(1.0f + e);
          pv4[i] = (kbase + 8 * g + i > qi) ? 0.0f : p;
        }
        u[2 * g] = pack2bf(pv4[0], pv4[1]);
        u[2 * g + 1] = pack2bf(pv4[2], pv4[3]);
      }
    } else {
#pragma unroll
      for (int g = 0; g < 4; g++) {
        float pv4[4];
#pragma unroll
        for (int i = 0; i < 4; i++) {
          float s = st[4 * g + i];
          float e = __builtin_amdgcn_exp2f(s * C1 + C2);
          pv4[i] = __builtin_amdgcn_rcpf(1.0f + e);
        }
        u[2 * g] = pack2bf(pv4[0], pv4[1]);
        u[2 * g + 1] = pack2bf(pv4[2], pv4[3]);
      }
    }

    // ---- T12: in-register re-layout to PV A-operand via permlane32_swap (verified) ----
    union { unsigned wd[4]; s16x8 v; } pa0, pa1;
    {
      auto r02 = __builtin_amdgcn_permlane32_swap(u[0], u[2], false, false);
      auto r13 = __builtin_amdgcn_permlane32_swap(u[1], u[3], false, false);
      auto r46 = __builtin_amdgcn_permlane32_swap(u[4], u[6], false, false);
      auto r57 = __builtin_amdgcn_permlane32_swap(u[5], u[7], false, false);
      pa0.wd[0] = r02[0]; pa0.wd[1] = r13[0]; pa0.wd[2] = r02[1]; pa0.wd[3] = r13[1];
      pa1.wd[0] = r46[0]; pa1.wd[1] = r57[0]; pa1.wd[2] = r46[1]; pa1.wd[3] = r57[1];
    }

    // ---- partial O += P V over this k32 (P register-resident) ----
#pragma unroll
    for (int dt = 0; dt < 2; dt++) {
      s16x8 vf0 = *(const s16x8*)&Vs[buf][dt * 32 + l31][kh * 32 + hi * 8];
      oacc[dt] = mfma32(pa0.v, vf0, oacc[dt]);
      s16x8 vf1 = *(const s16x8*)&Vs[buf][dt * 32 + l31][kh * 32 + 16 + hi * 8];
      oacc[dt] = mfma32(pa1.v, vf1, oacc[dt]);
    }
  }

  // ---- epilogue: reduce the two k-halves via LDS scratch, then store ----
  __syncthreads();  // all K/V reads done; Ks space reusable as Osc
  if (kh == 1) {
#pragma unroll
    for (int dt = 0; dt < 2; dt++)
#pragma unroll
      for (int reg = 0; reg < 16; reg++) {
        int ql = (reg & 3) + 8 * (reg >> 2) + 4 * hi;
        Osc[(qs * 32 + ql) * 66 + dt * 32 + l31] = oacc[dt][reg];
      }
  }
  __syncthreads();
  if (kh == 0) {
#pragma unroll
    for (int dt = 0; dt < 2; dt++)
#pragma unroll
      for (int reg = 0; reg < 16; reg++) {
        int ql = (reg & 3) + 8 * (reg >> 2) + 4 * hi;
        float v = oacc[dt][reg] + Osc[(qs * 32 + ql) * 66 + dt * 32 + l31];
        int row = q0 + qs * 32 + ql;
        int col = h * 64 + dt * 32 + l31;
        size_t idx = (size_t)(b * SQ_ + row) * D_ + col;
        out0[idx] = v;
        atv_bf[idx] = f2bf(v);
      }
  }
}

extern "C" void kernel_launch(void* const* d_in, const int* in_sizes, int n_in,
                              void* d_out, int out_size, void* d_ws, size_t ws_size,
                              hipStream_t stream) {
  const float* q      = (const float*)d_in[0];
  const float* kv     = (const float*)d_in[1];
  const float* Wq     = (const float*)d_in[2];
  const float* Wkv    = (const float*)d_in[3];
  const float* vgamma = (const float*)d_in[4];
  const float* vbeta  = (const float*)d_in[5];
  const float* Wproj  = (const float*)d_in[6];
  float* out0 = (float*)d_out;
  float* out1 = out0 + (size_t)B_ * SQ_ * D_;

  char* p = (char*)d_ws;
  u16* q_bf  = (u16*)p; p += (size_t)B_ * SQ_ * D_ * 2;
  u16* kv_bf = (u16*)p; p += (size_t)B_ * SKV_ * D_ * 2;
  u16* WqT   = (u16*)p; p += (size_t)D_ * D_ * 2;
  u16* WkvT  = (u16*)p; p += (size_t)2 * D_ * D_ * 2;
  u16* WprT  = (u16*)p; p += (size_t)D_ * D_ * 2;
  u16* qh    = (u16*)p; p += (size_t)B_ * SQ_ * D_ * 2;
  u16* kh    = (u16*)p; p += (size_t)B_ * SKV_ * D_ * 2;
  u16* vt    = (u16*)p; p += (size_t)B_ * H_ * HD_ * SKV_ * 2;
  u16* atv   = (u16*)p; p += (size_t)B_ * SQ_ * D_ * 2;

  prep_kernel<<<dim3(12288), 256, 0, stream>>>(q, q_bf, kv, kv_bf, Wq, WqT, Wkv, WkvT, Wproj, WprT);

  gemm_qkv<<<dim3(768), 256, 0, stream>>>(q_bf, WqT, qh, kv_bf, WkvT, kh, vgamma, vbeta, vt);

  attn_kernel<<<dim3(32, 32), 256, 0, stream>>>(qh, kh, vt, out0, atv);

  gemm_proj<<<dim3(512), 256, 0, stream>>>(atv, WprT, out1);
}